// Round 11
// baseline (1734.279 us; speedup 1.0000x reference)
//
#include <hip/hip_runtime.h>
#include <math.h>

// Residual VQ: x (262144,128) fp32, codebooks (3,256,128) fp32.
// Output: [indices as float (262144*3)] ++ [quantized (262144*128)].
//
// ARITHMETIC CONTRACT (absmax=0 — do not change):
//   M_k  = OpenBLAS sgemm K-loop: sequential FMA chain j=0..127, acc init 0
//   A    = np.sum(r*r): pairwise_sum 8-accumulator scheme, products rounded
//          separately (fma(x,x,0) = single-rounded product, then separate add)
//   d2_k = (A - 2.0f*M_k) + B_k ; argmin strict < ascending k
//   residual: r1 = x - q0, r2 = r1 - q1 — in-place global scratch, ref order
//   quantized = (q0 + q1) + q2 elementwise fp32, ref order
//
// ROUND 15 CHANGE: bound-series evidence (4->64, 5->48, 6->40 VGPRs) shows
// hipcc caps regs at ~512/(2*bound) — occupancy >4 blocks/CU needs a <48-reg
// working set. This round attacks the OTHER axis: the VALU stream. 157.3 TF
// fp32 requires v_pk_fma_f32 (2 FMA/instr); we've issued scalar v_fma all
// session (true floor 164us, not 328). Pack ENTRY-PAIRS per f32x2 acc — each
// component keeps its own sequential-j chain (bit-exact; pk rounds each half
// like v_fma). A-stripes pack pairwise with fma2(r,r,0)+separate pk-add
// (same roundings as sq_rn+add; tree combine order preserved). A pre-kernel
// interleaves the codebook into d_ws (384KB) pair-major per (c,jchunk) slab:
// pk operand {cb[2p][j],cb[2p+1][j]} becomes contiguous 64B s_load_dwordx16
// runs, shared across waves in K$. TE=16 (8 f32x2 accs = 16 VGPR) shrinks
// the working set toward the <48 band for next round's occupancy push; costs
// 4 residual sweeps/cb (L1/L2-resident). Bound stays 4: isolate pk cleanly.

constexpr int kItems = 262144;
constexpr int kDim   = 128;
constexpr int kNcb   = 3;
constexpr int kK     = 256;
constexpr int kBlock = 256;
constexpr int kIPB   = 64;         // items per block (one per lane)
constexpr int kEPW   = 64;         // entries per wave
constexpr int TE     = 16;         // entries per sub-tile (8 f32x2 accs)
constexpr int NJC    = kDim / 8;   // 16 dim-chunks of 8

typedef float f32x2 __attribute__((ext_vector_type(2)));

__device__ __forceinline__ float sq_rn(float x) {
    return __builtin_fmaf(x, x, 0.0f);
}
__device__ __forceinline__ f32x2 fma2(f32x2 a, f32x2 b, f32x2 c) {
    return __builtin_elementwise_fma(a, b, c);   // v_pk_fma_f32
}

// numpy pairwise_sum, n=128 (for the B-table)
template <typename F>
__device__ __forceinline__ float np_pairwise128(F term) {
    float r0 = term(0), r1 = term(1), r2 = term(2), r3 = term(3),
          r4 = term(4), r5 = term(5), r6 = term(6), r7 = term(7);
    #pragma unroll
    for (int i = 8; i < 128; i += 8) {
        r0 = r0 + term(i + 0); r1 = r1 + term(i + 1);
        r2 = r2 + term(i + 2); r3 = r3 + term(i + 3);
        r4 = r4 + term(i + 4); r5 = r5 + term(i + 5);
        r6 = r6 + term(i + 6); r7 = r7 + term(i + 7);
    }
    return ((r0 + r1) + (r2 + r3)) + ((r4 + r5) + (r6 + r7));
}

// ---------- pre-kernel: B-table (768 floats) + interleaved codebook cbI.
// cbI layout: float index = (((c*16 + jc)*128 + p)*8 + jw)*2 + h
//   = pair-major 64B runs per (c,jc) slab; h in {0,1} = entries 2p, 2p+1.
__global__ void rvq_prep(const float* __restrict__ cb,
                         float* __restrict__ Bt,
                         float* __restrict__ cbI)
{
    const int tid = blockIdx.x * 256 + threadIdx.x;   // 192*256 = 49152
    const int jw = tid & 7;
    const int p  = (tid >> 3) & 127;
    const int jc = (tid >> 10) & 15;
    const int c  = tid >> 14;
    const int j  = jc * 8 + jw;
    const float lo = cb[((size_t)c * kK + 2 * p) * kDim + j];
    const float hi = cb[((size_t)c * kK + 2 * p + 1) * kDim + j];
    cbI[(size_t)tid * 2]     = lo;
    cbI[(size_t)tid * 2 + 1] = hi;
    if (tid < kNcb * kK) {
        const float* row = cb + (size_t)tid * kDim;
        Bt[tid] = np_pairwise128([&](int jj) { return sq_rn(row[jj]); });
    }
}

// pair q of this sub-tile: 8 f32x2 = 64B contiguous (s_load_dwordx16)
#define MPAIR(q) { \
    const f32x2* rp = slab + (size_t)(pbase + (q)) * 8; \
    m##q = fma2(s0, rp[0], m##q); \
    m##q = fma2(s1, rp[1], m##q); \
    m##q = fma2(s2, rp[2], m##q); \
    m##q = fma2(s3, rp[3], m##q); \
    m##q = fma2(s4, rp[4], m##q); \
    m##q = fma2(s5, rp[5], m##q); \
    m##q = fma2(s6, rp[6], m##q); \
    m##q = fma2(s7, rp[7], m##q); }

#define EPI2(q) { \
    float t0 = __builtin_fmaf(-2.0f, m##q.x, A) + Bt[c * kK + kb + 2*(q)]; \
    if (t0 < best) { best = t0; bi = kb + 2*(q); } \
    float t1 = __builtin_fmaf(-2.0f, m##q.y, A) + Bt[c * kK + kb + 2*(q) + 1]; \
    if (t1 < best) { best = t1; bi = kb + 2*(q) + 1; } }

#define SUBTILE(SB, DO_A) { \
    const int kb = gbase + (SB) * TE; \
    const int pbase = (gbase >> 1) + (SB) * 8; \
    f32x2 m0 = Z2, m1 = Z2, m2 = Z2, m3 = Z2, \
          m4 = Z2, m5 = Z2, m6 = Z2, m7 = Z2; \
    f32x2 A01 = Z2, A23 = Z2, A45 = Z2, A67 = Z2; \
    float4 ra = rrow4[0], rb = rrow4[1]; \
    _Pragma("unroll 1") \
    for (int jc = 0; jc < NJC; ++jc) { \
        float4 na = ra, nb = rb; \
        if (jc < NJC - 1) { na = rrow4[2*jc+2]; nb = rrow4[2*jc+3]; } \
        const f32x2 s0 = {ra.x, ra.x}, s1 = {ra.y, ra.y}, \
                    s2 = {ra.z, ra.z}, s3 = {ra.w, ra.w}, \
                    s4 = {rb.x, rb.x}, s5 = {rb.y, rb.y}, \
                    s6 = {rb.z, rb.z}, s7 = {rb.w, rb.w}; \
        if (DO_A) { \
            const f32x2 rxy = {ra.x, ra.y}, rzw = {ra.z, ra.w}; \
            const f32x2 txy = {rb.x, rb.y}, tzw = {rb.z, rb.w}; \
            A01 = A01 + fma2(rxy, rxy, Z2);   /* round(prod), separate add */ \
            A23 = A23 + fma2(rzw, rzw, Z2); \
            A45 = A45 + fma2(txy, txy, Z2); \
            A67 = A67 + fma2(tzw, tzw, Z2); \
        } \
        const f32x2* slab = (const f32x2*)cbI + ((size_t)(c * 16 + jc) * 128) * 8; \
        MPAIR(0) MPAIR(1) MPAIR(2) MPAIR(3) MPAIR(4) MPAIR(5) MPAIR(6) MPAIR(7) \
        ra = na; rb = nb; \
    } \
    if (DO_A) \
        A = ((A01.x + A01.y) + (A23.x + A23.y)) + ((A45.x + A45.y) + (A67.x + A67.y)); \
    EPI2(0) EPI2(1) EPI2(2) EPI2(3) EPI2(4) EPI2(5) EPI2(6) EPI2(7) \
}

__global__ __launch_bounds__(kBlock, 4) void rvq_kernel(
    const float* __restrict__ x,
    const float* __restrict__ cb,
    const float* __restrict__ Bt,
    const float* __restrict__ cbI,
    float* __restrict__ out)
{
    __shared__ float s_bestv[kBlock];
    __shared__ int   s_besti[kBlock];

    const int t = threadIdx.x;
    const f32x2 Z2 = {0.0f, 0.0f};

    // wave id PROVABLY uniform so codebook addrs become s_loads
    const int wav  = __builtin_amdgcn_readfirstlane(t >> 6);
    const int lane = t & 63;
    const int item = blockIdx.x * kIPB + lane;
    const int gbase = wav * kEPW;

    float* out_idx = out;                             // (items, 3) as float
    float* out_q   = out + (size_t)kItems * kNcb;     // (items, 128)

    const float* xrow = x + (size_t)item * kDim;          // cb0 residual
    const float* qrow = out_q + (size_t)item * kDim;      // cb1/2 residual

    int sel0 = 0, sel1 = 0, sel2 = 0;

    #pragma unroll 1
    for (int c = 0; c < kNcb; ++c) {
        const float* rrow = (c == 0) ? xrow : qrow;
        const float4* rrow4 = (const float4*)rrow;

        float A = 0.0f;
        float best = INFINITY;
        int bi = gbase;

        SUBTILE(0, 1)
        SUBTILE(1, 0)
        SUBTILE(2, 0)
        SUBTILE(3, 0)

        // ---- cross-wave argmin, ascending group order == numpy first-min
        s_bestv[t] = best;
        s_besti[t] = bi;
        __syncthreads();
        float bv = s_bestv[lane];
        int   bx = s_besti[lane];
        #pragma unroll
        for (int g = 1; g < kBlock / 64; ++g) {
            const float v  = s_bestv[g * 64 + lane];
            const int   ix = s_besti[g * 64 + lane];
            if (v < bv) { bv = v; bx = ix; }
        }
        if (c == 0) sel0 = bx; else if (c == 1) sel1 = bx; else sel2 = bx;

        // ---- residual update into the out_q scratch (skip after last cb)
        if (c < 2) {
            const int sel = (c == 0) ? sel0 : sel1;     // valid for item t&63
            const int it  = t & 63;
            const int qtr = t >> 6;
            const size_t rowbase = (size_t)(blockIdx.x * kIPB + it) * kDim;
            const float* srow = (c == 0) ? (x + rowbase)
                                         : (const float*)(out_q + rowbase);
            float* drow = out_q + rowbase;
            const float4* cw4 =
                (const float4*)(cb + ((size_t)c * kK + sel) * kDim);
            #pragma unroll
            for (int i2 = 0; i2 < 8; ++i2) {
                const int c16 = qtr * 8 + i2;
                const float4 w = cw4[c16];
                float4 rv = *(const float4*)(srow + c16 * 4);
                rv.x = rv.x - w.x;  rv.y = rv.y - w.y;   // one rounding each,
                rv.z = rv.z - w.z;  rv.w = rv.w - w.w;   // ref order
                *(float4*)(drow + c16 * 4) = rv;
            }
            __syncthreads();   // r ready for next c; also gates s_bestv reuse
        }
    }

    // ---- outputs (all r2 scratch reads preceded the last combine barrier)
    if (wav == 0) {
        out_idx[(size_t)item * kNcb + 0] = (float)sel0;
        out_idx[(size_t)item * kNcb + 1] = (float)sel1;
        out_idx[(size_t)item * kNcb + 2] = (float)sel2;
    }
    // quantized: thread t writes quarter (t>>6) of item (t&63), overwriting
    // the residual scratch with the final values
    {
        const int it  = t & 63;
        const int qtr = t >> 6;
        const int oitem = blockIdx.x * kIPB + it;
        const float4* q0v = (const float4*)(cb + ((size_t)0 * kK + sel0) * kDim);
        const float4* q1v = (const float4*)(cb + ((size_t)1 * kK + sel1) * kDim);
        const float4* q2v = (const float4*)(cb + ((size_t)2 * kK + sel2) * kDim);
        float4* qov = (float4*)(out_q + (size_t)oitem * kDim);
        #pragma unroll
        for (int i2 = 0; i2 < 8; ++i2) {
            const int c16 = qtr * 8 + i2;
            const float4 u = q0v[c16], v = q1v[c16], w = q2v[c16];
            float4 o;
            o.x = (u.x + v.x) + w.x;
            o.y = (u.y + v.y) + w.y;
            o.z = (u.z + v.z) + w.z;
            o.w = (u.w + v.w) + w.w;
            qov[c16] = o;   // ((0+q0)+q1)+q2 in fp32, ref order
        }
    }
}

extern "C" void kernel_launch(void* const* d_in, const int* in_sizes, int n_in,
                              void* d_out, int out_size, void* d_ws, size_t ws_size,
                              hipStream_t stream) {
    const float* x  = (const float*)d_in[0];
    const float* cb = (const float*)d_in[1];
    float* out = (float*)d_out;
    float* Bt  = (float*)d_ws;                 // 768 floats
    float* cbI = (float*)d_ws + 1024;          // 98304 floats (384 KB)
    rvq_prep<<<192, 256, 0, stream>>>(cb, Bt, cbI);
    rvq_kernel<<<kItems / kIPB, kBlock, 0, stream>>>(x, cb, Bt, cbI, out);
}

// Round 12
// 1352.697 us; speedup vs baseline: 1.2821x; 1.2821x over previous
//
#include <hip/hip_runtime.h>
#include <math.h>

// Residual VQ: x (262144,128) fp32, codebooks (3,256,128) fp32.
// Output: [indices as float (262144*3)] ++ [quantized (262144*128)].
//
// ARITHMETIC CONTRACT (absmax=0 — do not change):
//   M_k  = OpenBLAS sgemm K-loop: sequential FMA chain j=0..127, acc init 0
//   A    = np.sum(r*r): pairwise_sum 8-accumulator scheme, products rounded
//          separately (fmaf(x,x,0) = single-rounded product, blocks fusion)
//   d2_k = (A - 2.0f*M_k) + B_k ; argmin strict < ascending k
//          (fmaf(-2,M,A)+B == (A-2.0f*M)+B bit-exact)
//   residual: r1 = x - q0, r2 = r1 - q1 — in-place global scratch, ref order
//   quantized = (q0 + q1) + q2 elementwise fp32, ref order
//
// ROUND 16 CHANGE: busy time is invariant at ~430-450us across scalar/pk/TE
// shapes -> the remaining ~800us is STALL, and the only high-latency dep in
// the hot loop is the codebook s_load feed: 4 waves x disjoint 16KB slices
// thrash the 16KB scalar K$ (most batches = L2, 200-400cyc) and the ~112-SGPR
// window caps prefetch at ~2 jc iterations. Occupancy can't cover it (hipcc
// caps VGPRs at 512/(2*bound): 4->64, 5->48, 6->40). Fix: each wave STAGES
// its 16-entry sub-tile (8KB contiguous) into a WAVE-PRIVATE LDS slab
// (coalesced float4 + ds_write_b128 memcpy; no barriers needed) and reads
// operands via uniform ds_read_b128 (same-address broadcast, conflict-free,
// ~64cyc, 15-deep lgkm queue, no SGPR window). Hot-loop wait domains now
// clean: residual=vmcnt (prefetched), codebook=lgkm ds-only (s_load only in
// the Bt epilogue). TE=16 forced by LDS (4x8KB=32KB -> 4 blocks/CU); its
// extra residual sweeps cost ~100us (r15 data) — the stall win must exceed.
// All 4 sub-tiles peeled straight-line (r10), unroll 1 on jc. Bound stays 4.

constexpr int kItems = 262144;
constexpr int kDim   = 128;
constexpr int kNcb   = 3;
constexpr int kK     = 256;
constexpr int kBlock = 256;
constexpr int kIPB   = 64;         // items per block (one per lane)
constexpr int kEPW   = 64;         // entries per wave
constexpr int TE     = 16;         // entries per sub-tile (LDS slab)
constexpr int NJC    = kDim / 8;   // 16 dim-chunks of 8

__device__ __forceinline__ float sq_rn(float x) {
    return __builtin_fmaf(x, x, 0.0f);
}

// numpy pairwise_sum, n=128 (for the B-table)
template <typename F>
__device__ __forceinline__ float np_pairwise128(F term) {
    float r0 = term(0), r1 = term(1), r2 = term(2), r3 = term(3),
          r4 = term(4), r5 = term(5), r6 = term(6), r7 = term(7);
    #pragma unroll
    for (int i = 8; i < 128; i += 8) {
        r0 = r0 + term(i + 0); r1 = r1 + term(i + 1);
        r2 = r2 + term(i + 2); r3 = r3 + term(i + 3);
        r4 = r4 + term(i + 4); r5 = r5 + term(i + 5);
        r6 = r6 + term(i + 6); r7 = r7 + term(i + 7);
    }
    return ((r0 + r1) + (r2 + r3)) + ((r4 + r5) + (r6 + r7));
}

// ---------- pre-kernel: B_k = np.sum(cb*cb, axis=-1) into d_ws (768 floats)
__global__ void rvq_btable(const float* __restrict__ cb,
                           float* __restrict__ Bt)
{
    const int m = blockIdx.x * 256 + threadIdx.x;   // 3 blocks x 256 = 768
    const float* row = cb + (size_t)m * kDim;
    Bt[m] = np_pairwise128([&](int j) { return sq_rn(row[j]); });
}

#define X16(X) X(0) X(1) X(2) X(3) X(4) X(5) X(6) X(7) \
  X(8) X(9) X(10) X(11) X(12) X(13) X(14) X(15)

// entry e of the staged slab: uniform ds_read_b128 pair (broadcast to lanes);
// per-entry FMA chain stays sequential in j
#define MROW(e) { \
    const float4 ca = slab4[(e) * 32 + 2 * jc]; \
    const float4 cd = slab4[(e) * 32 + 2 * jc + 1]; \
    m##e = __builtin_fmaf(ra.x, ca.x, m##e); \
    m##e = __builtin_fmaf(ra.y, ca.y, m##e); \
    m##e = __builtin_fmaf(ra.z, ca.z, m##e); \
    m##e = __builtin_fmaf(ra.w, ca.w, m##e); \
    m##e = __builtin_fmaf(rb.x, cd.x, m##e); \
    m##e = __builtin_fmaf(rb.y, cd.y, m##e); \
    m##e = __builtin_fmaf(rb.z, cd.z, m##e); \
    m##e = __builtin_fmaf(rb.w, cd.w, m##e); }

#define MDECL(e) float m##e = 0.0f;

#define EPI(e) { \
    float tt = __builtin_fmaf(-2.0f, m##e, A) + Bt[c * kK + kb + (e)]; \
    if (tt < best) { best = tt; bi = kb + (e); } }

// one 16-entry sub-tile: stage slab (wave-private, no barrier), sweep dims
#define SUBTILE(KB, DO_A) { \
    const int kb = (KB); \
    { /* stage 8KB contiguous: 8 coalesced float4 + ds_write_b128 per lane */ \
      const float4* src4 = (const float4*)(cb + ((size_t)c * kK + kb) * kDim); \
      _Pragma("unroll") \
      for (int f = 0; f < 8; ++f) { const int u = f * 64 + lane; slabw[u] = src4[u]; } \
    } \
    X16(MDECL) \
    float a0 = 0.f, a1 = 0.f, a2 = 0.f, a3 = 0.f, \
          a4 = 0.f, a5 = 0.f, a6 = 0.f, a7 = 0.f; \
    float4 ra = rrow4[0], rb = rrow4[1]; \
    _Pragma("unroll 1") \
    for (int jc = 0; jc < NJC; ++jc) { \
        float4 na = ra, nb = rb; \
        if (jc < NJC - 1) { na = rrow4[2*jc+2]; nb = rrow4[2*jc+3]; } \
        if (DO_A) { \
            a0 = a0 + sq_rn(ra.x); a1 = a1 + sq_rn(ra.y); \
            a2 = a2 + sq_rn(ra.z); a3 = a3 + sq_rn(ra.w); \
            a4 = a4 + sq_rn(rb.x); a5 = a5 + sq_rn(rb.y); \
            a6 = a6 + sq_rn(rb.z); a7 = a7 + sq_rn(rb.w); \
        } \
        X16(MROW) \
        ra = na; rb = nb; \
    } \
    if (DO_A) \
        A = ((a0 + a1) + (a2 + a3)) + ((a4 + a5) + (a6 + a7)); \
    X16(EPI) \
}

__global__ __launch_bounds__(kBlock, 4) void rvq_kernel(
    const float* __restrict__ x,
    const float* __restrict__ cb,
    const float* __restrict__ Bt,
    float* __restrict__ out)
{
    __shared__ float s_cb[4 * TE * kDim];     // 32 KB: per-wave 16-entry slab
    __shared__ float s_bestv[kBlock];
    __shared__ int   s_besti[kBlock];

    const int t = threadIdx.x;

    // wave id PROVABLY uniform (keeps staging src + Bt on the scalar path)
    const int wav  = __builtin_amdgcn_readfirstlane(t >> 6);
    const int lane = t & 63;
    const int item = blockIdx.x * kIPB + lane;
    const int gbase = wav * kEPW;

    // this wave's private slab
    float4* slabw = (float4*)(s_cb + (size_t)wav * TE * kDim);
    const float4* slab4 = (const float4*)(s_cb + (size_t)wav * TE * kDim);

    float* out_idx = out;                             // (items, 3) as float
    float* out_q   = out + (size_t)kItems * kNcb;     // (items, 128)

    const float* xrow = x + (size_t)item * kDim;          // cb0 residual
    const float* qrow = out_q + (size_t)item * kDim;      // cb1/2 residual

    int sel0 = 0, sel1 = 0, sel2 = 0;

    #pragma unroll 1
    for (int c = 0; c < kNcb; ++c) {
        const float* rrow = (c == 0) ? xrow : qrow;
        const float4* rrow4 = (const float4*)rrow;

        float A = 0.0f;
        float best = INFINITY;
        int bi = gbase;

        SUBTILE(gbase,      1)
        SUBTILE(gbase + 16, 0)
        SUBTILE(gbase + 32, 0)
        SUBTILE(gbase + 48, 0)

        // ---- cross-wave argmin, ascending group order == numpy first-min
        s_bestv[t] = best;
        s_besti[t] = bi;
        __syncthreads();
        float bv = s_bestv[lane];
        int   bx = s_besti[lane];
        #pragma unroll
        for (int g = 1; g < kBlock / 64; ++g) {
            const float v  = s_bestv[g * 64 + lane];
            const int   ix = s_besti[g * 64 + lane];
            if (v < bv) { bv = v; bx = ix; }
        }
        if (c == 0) sel0 = bx; else if (c == 1) sel1 = bx; else sel2 = bx;

        // ---- residual update into the out_q scratch (skip after last cb)
        if (c < 2) {
            const int sel = (c == 0) ? sel0 : sel1;     // valid for item t&63
            const int it  = t & 63;
            const int qtr = t >> 6;
            const size_t rowbase = (size_t)(blockIdx.x * kIPB + it) * kDim;
            const float* srow = (c == 0) ? (x + rowbase)
                                         : (const float*)(out_q + rowbase);
            float* drow = out_q + rowbase;
            const float4* cw4 =
                (const float4*)(cb + ((size_t)c * kK + sel) * kDim);
            #pragma unroll
            for (int i2 = 0; i2 < 8; ++i2) {
                const int c16 = qtr * 8 + i2;
                const float4 w = cw4[c16];
                float4 rv = *(const float4*)(srow + c16 * 4);
                rv.x = rv.x - w.x;  rv.y = rv.y - w.y;   // one rounding each,
                rv.z = rv.z - w.z;  rv.w = rv.w - w.w;   // ref order
                *(float4*)(drow + c16 * 4) = rv;
            }
            __syncthreads();   // r ready for next c; also gates s_bestv reuse
        }
    }

    // ---- outputs (all r2 scratch reads preceded the last combine barrier)
    if (wav == 0) {
        out_idx[(size_t)item * kNcb + 0] = (float)sel0;
        out_idx[(size_t)item * kNcb + 1] = (float)sel1;
        out_idx[(size_t)item * kNcb + 2] = (float)sel2;
    }
    // quantized: thread t writes quarter (t>>6) of item (t&63), overwriting
    // the residual scratch with the final values
    {
        const int it  = t & 63;
        const int qtr = t >> 6;
        const int oitem = blockIdx.x * kIPB + it;
        const float4* q0v = (const float4*)(cb + ((size_t)0 * kK + sel0) * kDim);
        const float4* q1v = (const float4*)(cb + ((size_t)1 * kK + sel1) * kDim);
        const float4* q2v = (const float4*)(cb + ((size_t)2 * kK + sel2) * kDim);
        float4* qov = (float4*)(out_q + (size_t)oitem * kDim);
        #pragma unroll
        for (int i2 = 0; i2 < 8; ++i2) {
            const int c16 = qtr * 8 + i2;
            const float4 u = q0v[c16], v = q1v[c16], w = q2v[c16];
            float4 o;
            o.x = (u.x + v.x) + w.x;
            o.y = (u.y + v.y) + w.y;
            o.z = (u.z + v.z) + w.z;
            o.w = (u.w + v.w) + w.w;
            qov[c16] = o;   // ((0+q0)+q1)+q2 in fp32, ref order
        }
    }
}

extern "C" void kernel_launch(void* const* d_in, const int* in_sizes, int n_in,
                              void* d_out, int out_size, void* d_ws, size_t ws_size,
                              hipStream_t stream) {
    const float* x  = (const float*)d_in[0];
    const float* cb = (const float*)d_in[1];
    float* out = (float*)d_out;
    float* Bt  = (float*)d_ws;     // 768 floats
    rvq_btable<<<kNcb, 256, 0, stream>>>(cb, Bt);
    rvq_kernel<<<kItems / kIPB, kBlock, 0, stream>>>(x, cb, Bt, out);
}

// Round 13
// 1233.567 us; speedup vs baseline: 1.4059x; 1.0966x over previous
//
#include <hip/hip_runtime.h>
#include <math.h>

// Residual VQ: x (262144,128) fp32, codebooks (3,256,128) fp32.
// Output: [indices as float (262144*3)] ++ [quantized (262144*128)].
//
// ARITHMETIC CONTRACT (absmax=0 — do not change):
//   M_k  = OpenBLAS sgemm K-loop: sequential FMA chain j=0..127, acc init 0
//   A    = np.sum(r*r): pairwise_sum 8-accumulator scheme, products rounded
//          separately (fmaf(x,x,0) = single-rounded product, blocks fusion)
//   d2_k = (A - 2.0f*M_k) + B_k ; argmin strict < ascending k
//          (fmaf(-2,M,A)+B == (A-2.0f*M)+B bit-exact)
//   residual: r1 = x - q0, r2 = r1 - q1 — in-place global scratch, ref order
//   quantized = (q0 + q1) + q2 elementwise fp32, ref order
//
// ROUND 17 CHANGE: r16 proved the LDS-slab feed fixes the stall (VALUBusy
// 33->76.6%: ds_read = 64cyc latency, 15-deep lgkm queue, no SGPR window) but
// TE=16 re-imposed the sweep tax (FETCH 800MB, WRITE 1.2GB churn). r12
// proved TE=32 is the FETCH optimum (426MB). Compose both: TE=32 LDS slab =
// 4 waves x 16KB = 64KB/block, which fits the static limit by ALIASING the
// argmin-combine buffers into the slab (they are live only between sweeps
// when the slab is dead; one extra barrier per cb makes the alias safe).
// __launch_bounds__(256,2): hipcc's cap 512/(2*bound)=128 VGPRs — first
// config where regs, LDS, and the scalar window all have headroom; 2
// blocks/CU (LDS-pinned) = 8 waves/CU covering 64cyc LDS latency, not 300cyc
// L2. Everything else identical to r16 (verified absmax=0).

constexpr int kItems = 262144;
constexpr int kDim   = 128;
constexpr int kNcb   = 3;
constexpr int kK     = 256;
constexpr int kBlock = 256;
constexpr int kIPB   = 64;         // items per block (one per lane)
constexpr int kEPW   = 64;         // entries per wave
constexpr int TE     = 32;         // entries per sub-tile (LDS slab)
constexpr int NJC    = kDim / 8;   // 16 dim-chunks of 8

__device__ __forceinline__ float sq_rn(float x) {
    return __builtin_fmaf(x, x, 0.0f);
}

// numpy pairwise_sum, n=128 (for the B-table)
template <typename F>
__device__ __forceinline__ float np_pairwise128(F term) {
    float r0 = term(0), r1 = term(1), r2 = term(2), r3 = term(3),
          r4 = term(4), r5 = term(5), r6 = term(6), r7 = term(7);
    #pragma unroll
    for (int i = 8; i < 128; i += 8) {
        r0 = r0 + term(i + 0); r1 = r1 + term(i + 1);
        r2 = r2 + term(i + 2); r3 = r3 + term(i + 3);
        r4 = r4 + term(i + 4); r5 = r5 + term(i + 5);
        r6 = r6 + term(i + 6); r7 = r7 + term(i + 7);
    }
    return ((r0 + r1) + (r2 + r3)) + ((r4 + r5) + (r6 + r7));
}

// ---------- pre-kernel: B_k = np.sum(cb*cb, axis=-1) into d_ws (768 floats)
__global__ void rvq_btable(const float* __restrict__ cb,
                           float* __restrict__ Bt)
{
    const int m = blockIdx.x * 256 + threadIdx.x;   // 3 blocks x 256 = 768
    const float* row = cb + (size_t)m * kDim;
    Bt[m] = np_pairwise128([&](int j) { return sq_rn(row[j]); });
}

#define X32(X) X(0) X(1) X(2) X(3) X(4) X(5) X(6) X(7) \
  X(8) X(9) X(10) X(11) X(12) X(13) X(14) X(15) \
  X(16) X(17) X(18) X(19) X(20) X(21) X(22) X(23) \
  X(24) X(25) X(26) X(27) X(28) X(29) X(30) X(31)

// entry e of the staged slab: uniform ds_read_b128 pair (broadcast), address
// = wave base + jc*32B (one v_add per jc) + e*512{+16} immediate offsets;
// per-entry FMA chain stays sequential in j
#define MROW(e) { \
    const float4 ca = slab4[(e) * 32 + 2 * jc]; \
    const float4 cd = slab4[(e) * 32 + 2 * jc + 1]; \
    m##e = __builtin_fmaf(ra.x, ca.x, m##e); \
    m##e = __builtin_fmaf(ra.y, ca.y, m##e); \
    m##e = __builtin_fmaf(ra.z, ca.z, m##e); \
    m##e = __builtin_fmaf(ra.w, ca.w, m##e); \
    m##e = __builtin_fmaf(rb.x, cd.x, m##e); \
    m##e = __builtin_fmaf(rb.y, cd.y, m##e); \
    m##e = __builtin_fmaf(rb.z, cd.z, m##e); \
    m##e = __builtin_fmaf(rb.w, cd.w, m##e); }

#define MDECL(e) float m##e = 0.0f;

#define EPI(e) { \
    float tt = __builtin_fmaf(-2.0f, m##e, A) + Bt[c * kK + kb + (e)]; \
    if (tt < best) { best = tt; bi = kb + (e); } }

// one 32-entry sub-tile: stage 16KB slab (wave-private, no barrier), sweep
#define SUBTILE(KB, DO_A) { \
    const int kb = (KB); \
    { /* stage 16KB contiguous: 16 coalesced float4 + ds_write_b128 per lane */ \
      const float4* src4 = (const float4*)(cb + ((size_t)c * kK + kb) * kDim); \
      _Pragma("unroll") \
      for (int f = 0; f < 16; ++f) { const int u = f * 64 + lane; slabw[u] = src4[u]; } \
    } \
    X32(MDECL) \
    float a0 = 0.f, a1 = 0.f, a2 = 0.f, a3 = 0.f, \
          a4 = 0.f, a5 = 0.f, a6 = 0.f, a7 = 0.f; \
    float4 ra = rrow4[0], rb = rrow4[1]; \
    _Pragma("unroll 1") \
    for (int jc = 0; jc < NJC; ++jc) { \
        float4 na = ra, nb = rb; \
        if (jc < NJC - 1) { na = rrow4[2*jc+2]; nb = rrow4[2*jc+3]; } \
        if (DO_A) { \
            a0 = a0 + sq_rn(ra.x); a1 = a1 + sq_rn(ra.y); \
            a2 = a2 + sq_rn(ra.z); a3 = a3 + sq_rn(ra.w); \
            a4 = a4 + sq_rn(rb.x); a5 = a5 + sq_rn(rb.y); \
            a6 = a6 + sq_rn(rb.z); a7 = a7 + sq_rn(rb.w); \
        } \
        X32(MROW) \
        ra = na; rb = nb; \
    } \
    if (DO_A) \
        A = ((a0 + a1) + (a2 + a3)) + ((a4 + a5) + (a6 + a7)); \
    X32(EPI) \
}

__global__ __launch_bounds__(kBlock, 2) void rvq_kernel(
    const float* __restrict__ x,
    const float* __restrict__ cb,
    const float* __restrict__ Bt,
    float* __restrict__ out)
{
    // 64KB: per-wave 32-entry slab. The argmin-combine buffers ALIAS the
    // first 2KB (wave 0's slab) — only touched between sweeps (slab dead),
    // guarded by barriers; restaged next cb.
    __shared__ float s_cb[4 * TE * kDim];
    float* s_bestv = s_cb;                    // [256] floats
    int*   s_besti = (int*)(s_cb + kBlock);   // [256] ints

    const int t = threadIdx.x;

    // wave id PROVABLY uniform (keeps staging src + Bt on the scalar path)
    const int wav  = __builtin_amdgcn_readfirstlane(t >> 6);
    const int lane = t & 63;
    const int item = blockIdx.x * kIPB + lane;
    const int gbase = wav * kEPW;

    // this wave's private slab
    float4* slabw = (float4*)(s_cb + (size_t)wav * TE * kDim);
    const float4* slab4 = (const float4*)(s_cb + (size_t)wav * TE * kDim);

    float* out_idx = out;                             // (items, 3) as float
    float* out_q   = out + (size_t)kItems * kNcb;     // (items, 128)

    const float* xrow = x + (size_t)item * kDim;          // cb0 residual
    const float* qrow = out_q + (size_t)item * kDim;      // cb1/2 residual

    int sel0 = 0, sel1 = 0, sel2 = 0;

    #pragma unroll 1
    for (int c = 0; c < kNcb; ++c) {
        const float* rrow = (c == 0) ? xrow : qrow;
        const float4* rrow4 = (const float4*)rrow;

        float A = 0.0f;
        float best = INFINITY;
        int bi = gbase;

        SUBTILE(gbase,      1)
        SUBTILE(gbase + 32, 0)

        // ---- all waves done sweeping: slab region dead, alias is safe
        __syncthreads();

        // ---- cross-wave argmin, ascending group order == numpy first-min
        s_bestv[t] = best;
        s_besti[t] = bi;
        __syncthreads();
        float bv = s_bestv[lane];
        int   bx = s_besti[lane];
        #pragma unroll
        for (int g = 1; g < kBlock / 64; ++g) {
            const float v  = s_bestv[g * 64 + lane];
            const int   ix = s_besti[g * 64 + lane];
            if (v < bv) { bv = v; bx = ix; }
        }
        if (c == 0) sel0 = bx; else if (c == 1) sel1 = bx; else sel2 = bx;

        // ---- residual update into the out_q scratch (skip after last cb)
        if (c < 2) {
            const int sel = (c == 0) ? sel0 : sel1;     // valid for item t&63
            const int it  = t & 63;
            const int qtr = t >> 6;
            const size_t rowbase = (size_t)(blockIdx.x * kIPB + it) * kDim;
            const float* srow = (c == 0) ? (x + rowbase)
                                         : (const float*)(out_q + rowbase);
            float* drow = out_q + rowbase;
            const float4* cw4 =
                (const float4*)(cb + ((size_t)c * kK + sel) * kDim);
            #pragma unroll
            for (int i2 = 0; i2 < 8; ++i2) {
                const int c16 = qtr * 8 + i2;
                const float4 w = cw4[c16];
                float4 rv = *(const float4*)(srow + c16 * 4);
                rv.x = rv.x - w.x;  rv.y = rv.y - w.y;   // one rounding each,
                rv.z = rv.z - w.z;  rv.w = rv.w - w.w;   // ref order
                *(float4*)(drow + c16 * 4) = rv;
            }
            __syncthreads();   // r + combine buffers ready for next c
        }
    }

    // ---- outputs (all r2 scratch reads preceded the last combine barrier)
    if (wav == 0) {
        out_idx[(size_t)item * kNcb + 0] = (float)sel0;
        out_idx[(size_t)item * kNcb + 1] = (float)sel1;
        out_idx[(size_t)item * kNcb + 2] = (float)sel2;
    }
    // quantized: thread t writes quarter (t>>6) of item (t&63), overwriting
    // the residual scratch with the final values
    {
        const int it  = t & 63;
        const int qtr = t >> 6;
        const int oitem = blockIdx.x * kIPB + it;
        const float4* q0v = (const float4*)(cb + ((size_t)0 * kK + sel0) * kDim);
        const float4* q1v = (const float4*)(cb + ((size_t)1 * kK + sel1) * kDim);
        const float4* q2v = (const float4*)(cb + ((size_t)2 * kK + sel2) * kDim);
        float4* qov = (float4*)(out_q + (size_t)oitem * kDim);
        #pragma unroll
        for (int i2 = 0; i2 < 8; ++i2) {
            const int c16 = qtr * 8 + i2;
            const float4 u = q0v[c16], v = q1v[c16], w = q2v[c16];
            float4 o;
            o.x = (u.x + v.x) + w.x;
            o.y = (u.y + v.y) + w.y;
            o.z = (u.z + v.z) + w.z;
            o.w = (u.w + v.w) + w.w;
            qov[c16] = o;   // ((0+q0)+q1)+q2 in fp32, ref order
        }
    }
}

extern "C" void kernel_launch(void* const* d_in, const int* in_sizes, int n_in,
                              void* d_out, int out_size, void* d_ws, size_t ws_size,
                              hipStream_t stream) {
    const float* x  = (const float*)d_in[0];
    const float* cb = (const float*)d_in[1];
    float* out = (float*)d_out;
    float* Bt  = (float*)d_ws;     // 768 floats
    rvq_btable<<<kNcb, 256, 0, stream>>>(cb, Bt);
    rvq_kernel<<<kItems / kIPB, kBlock, 0, stream>>>(x, cb, Bt, out);
}